// Round 1
// baseline (740.104 us; speedup 1.0000x reference)
//
#include <hip/hip_runtime.h>
#include <math.h>

#define NN 100000
#define NE 1200000
#define DD 64
#define SCAN_B 1024
#define NCHUNK ((NN + SCAN_B - 1) / SCAN_B)   // 98

// ---- degree count (int atomics) ----
__global__ __launch_bounds__(256) void k_degrees(const int* __restrict__ src,
                                                 const int* __restrict__ dst,
                                                 int* __restrict__ out_deg,
                                                 int* __restrict__ in_deg) {
  int e = blockIdx.x * blockDim.x + threadIdx.x;
  if (e < NE) {
    atomicAdd(&out_deg[src[e]], 1);
    atomicAdd(&in_deg[dst[e]], 1);
  }
}

// ---- norms ----
__global__ __launch_bounds__(256) void k_norms(const int* __restrict__ out_deg,
                                               const int* __restrict__ in_deg,
                                               float* __restrict__ out_norm,
                                               float* __restrict__ in_norm) {
  int i = blockIdx.x * blockDim.x + threadIdx.x;
  if (i < NN) {
    out_norm[i] = rsqrtf(fmaxf((float)out_deg[i], 1.0f));
    in_norm[i]  = rsqrtf(fmaxf((float)in_deg[i], 1.0f));
  }
}

// ---- hierarchical exclusive scan of in_deg -> row_ptr ----
__global__ __launch_bounds__(SCAN_B) void k_scan_partial(const int* __restrict__ in_deg,
                                                         int* __restrict__ partial) {
  __shared__ int sd[SCAN_B];
  int tid = threadIdx.x;
  int i = blockIdx.x * SCAN_B + tid;
  sd[tid] = (i < NN) ? in_deg[i] : 0;
  __syncthreads();
  for (int s = SCAN_B / 2; s > 0; s >>= 1) {
    if (tid < s) sd[tid] += sd[tid + s];
    __syncthreads();
  }
  if (tid == 0) partial[blockIdx.x] = sd[0];
}

__global__ __launch_bounds__(128) void k_scan_chunks(int* __restrict__ partial,
                                                     int* __restrict__ row_ptr) {
  __shared__ int sd[128];
  int tid = threadIdx.x;
  int v = (tid < NCHUNK) ? partial[tid] : 0;
  sd[tid] = v;
  __syncthreads();
  for (int off = 1; off < 128; off <<= 1) {
    int t = (tid >= off) ? sd[tid - off] : 0;
    __syncthreads();
    sd[tid] += t;
    __syncthreads();
  }
  if (tid < NCHUNK) partial[tid] = sd[tid] - v;   // exclusive chunk offset
  if (tid == 127) row_ptr[NN] = sd[127];          // total edge count
}

__global__ __launch_bounds__(SCAN_B) void k_scan_final(const int* __restrict__ in_deg,
                                                       const int* __restrict__ partial,
                                                       int* __restrict__ row_ptr) {
  __shared__ int sd[SCAN_B];
  int tid = threadIdx.x;
  int i = blockIdx.x * SCAN_B + tid;
  int v = (i < NN) ? in_deg[i] : 0;
  sd[tid] = v;
  __syncthreads();
  for (int off = 1; off < SCAN_B; off <<= 1) {
    int t = (tid >= off) ? sd[tid - off] : 0;
    __syncthreads();
    sd[tid] += t;
    __syncthreads();
  }
  if (i < NN) row_ptr[i] = partial[blockIdx.x] + sd[tid] - v;  // exclusive
}

// ---- bucket edges by dst ----
__global__ __launch_bounds__(256) void k_bucket(const int* __restrict__ src,
                                                const int* __restrict__ dst,
                                                const int* __restrict__ row_ptr,
                                                int* __restrict__ cursor,
                                                int* __restrict__ col) {
  int e = blockIdx.x * blockDim.x + threadIdx.x;
  if (e < NE) {
    int d = dst[e];
    int p = atomicAdd(&cursor[d], 1);
    col[row_ptr[d] + p] = src[e];
  }
}

// ---- g = (x * out_norm[:,None]) @ W : wave per row, W column in regs ----
__global__ __launch_bounds__(256) void k_gemm(const float* __restrict__ x,
                                              const float* __restrict__ onorm,
                                              const float* __restrict__ W,
                                              float* __restrict__ g) {
  const int lane = threadIdx.x & 63;
  const int wave = (blockIdx.x * blockDim.x + threadIdx.x) >> 6;
  const int nw = (gridDim.x * blockDim.x) >> 6;
  float w[DD];
#pragma unroll
  for (int k = 0; k < DD; ++k) w[k] = W[k * DD + lane];
  for (int r = wave; r < NN; r += nw) {
    float xr = x[r * DD + lane] * onorm[r];
    float acc = 0.0f;
#pragma unroll
    for (int k = 0; k < DD; ++k) acc = fmaf(__shfl(xr, k), w[k], acc);
    g[r * DD + lane] = acc;
  }
}

// ---- out[v] = elu(in_norm[v] * sum_{e in CSR[v]} g[col[e]] + b) ----
__global__ __launch_bounds__(256) void k_agg(const float* __restrict__ g,
                                             const int* __restrict__ row_ptr,
                                             const int* __restrict__ col,
                                             const float* __restrict__ in_norm,
                                             const float* __restrict__ bias,
                                             float* __restrict__ out) {
  const int lane = threadIdx.x & 63;
  const int wave = (blockIdx.x * blockDim.x + threadIdx.x) >> 6;
  const int nw = (gridDim.x * blockDim.x) >> 6;
  const float b = bias[lane];
  for (int v = wave; v < NN; v += nw) {
    const int beg = row_ptr[v];
    const int end = row_ptr[v + 1];
    float acc = 0.0f;
    for (int e = beg; e < end; ++e) {
      int s = __builtin_amdgcn_readfirstlane(col[e]);  // wave-uniform src node
      acc += g[s * DD + lane];                         // coalesced 256B row
    }
    float r = fmaf(acc, in_norm[v], b);
    out[v * DD + lane] = (r > 0.0f) ? r : expm1f(r);
  }
}

extern "C" void kernel_launch(void* const* d_in, const int* in_sizes, int n_in,
                              void* d_out, int out_size, void* d_ws, size_t ws_size,
                              hipStream_t stream) {
  (void)in_sizes; (void)n_in; (void)out_size; (void)ws_size;
  const float* feat = (const float*)d_in[0];
  const float* W0 = (const float*)d_in[1];
  const float* b0 = (const float*)d_in[2];
  const float* W1 = (const float*)d_in[3];
  const float* b1 = (const float*)d_in[4];
  const float* W2 = (const float*)d_in[5];
  const float* b2 = (const float*)d_in[6];
  const int* src = (const int*)d_in[7];
  const int* dst = (const int*)d_in[8];
  float* out = (float*)d_out;

  // workspace layout (~33 MB)
  char* p = (char*)d_ws;
  int* out_deg = (int*)p;   p += (size_t)NN * 4;
  int* in_deg  = (int*)p;   p += (size_t)NN * 4;
  float* out_norm = (float*)p; p += (size_t)NN * 4;
  float* in_norm  = (float*)p; p += (size_t)NN * 4;
  int* row_ptr = (int*)p;   p += (size_t)(NN + 64) * 4;
  int* cursor  = (int*)p;   p += (size_t)NN * 4;
  int* partial = (int*)p;   p += (size_t)256 * 4;
  int* col     = (int*)p;   p += (size_t)NE * 4;
  float* gbuf  = (float*)p; p += (size_t)NN * DD * 4;

  hipMemsetAsync(out_deg, 0, (size_t)NN * 2 * sizeof(int), stream);  // out_deg + in_deg
  hipMemsetAsync(cursor, 0, (size_t)NN * sizeof(int), stream);

  k_degrees<<<(NE + 255) / 256, 256, 0, stream>>>(src, dst, out_deg, in_deg);
  k_norms<<<(NN + 255) / 256, 256, 0, stream>>>(out_deg, in_deg, out_norm, in_norm);
  k_scan_partial<<<NCHUNK, SCAN_B, 0, stream>>>(in_deg, partial);
  k_scan_chunks<<<1, 128, 0, stream>>>(partial, row_ptr);
  k_scan_final<<<NCHUNK, SCAN_B, 0, stream>>>(in_deg, partial, row_ptr);
  k_bucket<<<(NE + 255) / 256, 256, 0, stream>>>(src, dst, row_ptr, cursor, col);

  const float* xs[3] = {feat, out, out};
  const float* Wl[3] = {W0, W1, W2};
  const float* bl[3] = {b0, b1, b2};
  for (int l = 0; l < 3; ++l) {
    k_gemm<<<1024, 256, 0, stream>>>(xs[l], out_norm, Wl[l], gbuf);
    k_agg<<<2048, 256, 0, stream>>>(gbuf, row_ptr, col, in_norm, bl[l], out);
  }
}

// Round 2
// 553.100 us; speedup vs baseline: 1.3381x; 1.3381x over previous
//
#include <hip/hip_runtime.h>
#include <math.h>

#define NN 100000
#define NE 1200000
#define DD 64
#define SCAN_B 1024
#define NCHUNK ((NN + SCAN_B - 1) / SCAN_B)   // 98

// ---- degree count (int atomics) ----
__global__ __launch_bounds__(256) void k_degrees(const int* __restrict__ src,
                                                 const int* __restrict__ dst,
                                                 int* __restrict__ out_deg,
                                                 int* __restrict__ in_deg) {
  int e = blockIdx.x * blockDim.x + threadIdx.x;
  if (e < NE) {
    atomicAdd(&out_deg[src[e]], 1);
    atomicAdd(&in_deg[dst[e]], 1);
  }
}

// ---- norms ----
__global__ __launch_bounds__(256) void k_norms(const int* __restrict__ out_deg,
                                               const int* __restrict__ in_deg,
                                               float* __restrict__ out_norm,
                                               float* __restrict__ in_norm) {
  int i = blockIdx.x * blockDim.x + threadIdx.x;
  if (i < NN) {
    out_norm[i] = rsqrtf(fmaxf((float)out_deg[i], 1.0f));
    in_norm[i]  = rsqrtf(fmaxf((float)in_deg[i], 1.0f));
  }
}

// ---- hierarchical exclusive scan of in_deg -> row_ptr ----
__global__ __launch_bounds__(SCAN_B) void k_scan_partial(const int* __restrict__ in_deg,
                                                         int* __restrict__ partial) {
  __shared__ int sd[SCAN_B];
  int tid = threadIdx.x;
  int i = blockIdx.x * SCAN_B + tid;
  sd[tid] = (i < NN) ? in_deg[i] : 0;
  __syncthreads();
  for (int s = SCAN_B / 2; s > 0; s >>= 1) {
    if (tid < s) sd[tid] += sd[tid + s];
    __syncthreads();
  }
  if (tid == 0) partial[blockIdx.x] = sd[0];
}

__global__ __launch_bounds__(128) void k_scan_chunks(int* __restrict__ partial,
                                                     int* __restrict__ row_ptr) {
  __shared__ int sd[128];
  int tid = threadIdx.x;
  int v = (tid < NCHUNK) ? partial[tid] : 0;
  sd[tid] = v;
  __syncthreads();
  for (int off = 1; off < 128; off <<= 1) {
    int t = (tid >= off) ? sd[tid - off] : 0;
    __syncthreads();
    sd[tid] += t;
    __syncthreads();
  }
  if (tid < NCHUNK) partial[tid] = sd[tid] - v;   // exclusive chunk offset
  if (tid == 127) row_ptr[NN] = sd[127];          // total edge count
}

__global__ __launch_bounds__(SCAN_B) void k_scan_final(const int* __restrict__ in_deg,
                                                       const int* __restrict__ partial,
                                                       int* __restrict__ row_ptr) {
  __shared__ int sd[SCAN_B];
  int tid = threadIdx.x;
  int i = blockIdx.x * SCAN_B + tid;
  int v = (i < NN) ? in_deg[i] : 0;
  sd[tid] = v;
  __syncthreads();
  for (int off = 1; off < SCAN_B; off <<= 1) {
    int t = (tid >= off) ? sd[tid - off] : 0;
    __syncthreads();
    sd[tid] += t;
    __syncthreads();
  }
  if (i < NN) row_ptr[i] = partial[blockIdx.x] + sd[tid] - v;  // exclusive
}

// ---- bucket edges by dst ----
__global__ __launch_bounds__(256) void k_bucket(const int* __restrict__ src,
                                                const int* __restrict__ dst,
                                                const int* __restrict__ row_ptr,
                                                int* __restrict__ cursor,
                                                int* __restrict__ col) {
  int e = blockIdx.x * blockDim.x + threadIdx.x;
  if (e < NE) {
    int d = dst[e];
    int p = atomicAdd(&cursor[d], 1);
    col[row_ptr[d] + p] = src[e];
  }
}

// ---- g = (x * out_norm[:,None]) @ W : wave per row, W column in regs ----
__global__ __launch_bounds__(256) void k_gemm(const float* __restrict__ x,
                                              const float* __restrict__ onorm,
                                              const float* __restrict__ W,
                                              float* __restrict__ g) {
  const int lane = threadIdx.x & 63;
  const int wave = (blockIdx.x * blockDim.x + threadIdx.x) >> 6;
  const int nw = (gridDim.x * blockDim.x) >> 6;
  float w[DD];
#pragma unroll
  for (int k = 0; k < DD; ++k) w[k] = W[k * DD + lane];
  for (int r = wave; r < NN; r += nw) {
    float xr = x[r * DD + lane] * onorm[r];
    float acc = 0.0f;
#pragma unroll
    for (int k = 0; k < DD; ++k) acc = fmaf(__shfl(xr, k), w[k], acc);
    g[r * DD + lane] = acc;
  }
}

// ---- out[v] = elu(in_norm[v] * sum_{e in CSR[v]} g[col[e]] + b) ----
// 8-wide edge unroll: 8 independent 256-B row loads in flight per wave
// (latency-bound gather -> MLP). Clamped indices + wave-uniform predicated
// adds avoid a serial tail loop.
__global__ __launch_bounds__(256) void k_agg(const float* __restrict__ g,
                                             const int* __restrict__ row_ptr,
                                             const int* __restrict__ col,
                                             const float* __restrict__ in_norm,
                                             const float* __restrict__ bias,
                                             float* __restrict__ out) {
  const int lane = threadIdx.x & 63;
  const int wave = (blockIdx.x * blockDim.x + threadIdx.x) >> 6;
  const int nw = (gridDim.x * blockDim.x) >> 6;
  const float b = bias[lane];
  for (int v = wave; v < NN; v += nw) {
    const int beg = row_ptr[v];
    const int end = row_ptr[v + 1];
    float acc = 0.0f;
    for (int e = beg; e < end; e += 8) {
      const int last = end - 1;
      const int s0 = col[e];
      const int s1 = col[min(e + 1, last)];
      const int s2 = col[min(e + 2, last)];
      const int s3 = col[min(e + 3, last)];
      const int s4 = col[min(e + 4, last)];
      const int s5 = col[min(e + 5, last)];
      const int s6 = col[min(e + 6, last)];
      const int s7 = col[min(e + 7, last)];
      const float v0 = g[(size_t)s0 * DD + lane];
      const float v1 = g[(size_t)s1 * DD + lane];
      const float v2 = g[(size_t)s2 * DD + lane];
      const float v3 = g[(size_t)s3 * DD + lane];
      const float v4 = g[(size_t)s4 * DD + lane];
      const float v5 = g[(size_t)s5 * DD + lane];
      const float v6 = g[(size_t)s6 * DD + lane];
      const float v7 = g[(size_t)s7 * DD + lane];
      acc += v0;
      acc += (e + 1 < end) ? v1 : 0.0f;
      acc += (e + 2 < end) ? v2 : 0.0f;
      acc += (e + 3 < end) ? v3 : 0.0f;
      acc += (e + 4 < end) ? v4 : 0.0f;
      acc += (e + 5 < end) ? v5 : 0.0f;
      acc += (e + 6 < end) ? v6 : 0.0f;
      acc += (e + 7 < end) ? v7 : 0.0f;
    }
    float r = fmaf(acc, in_norm[v], b);
    out[v * DD + lane] = (r > 0.0f) ? r : expm1f(r);
  }
}

extern "C" void kernel_launch(void* const* d_in, const int* in_sizes, int n_in,
                              void* d_out, int out_size, void* d_ws, size_t ws_size,
                              hipStream_t stream) {
  (void)in_sizes; (void)n_in; (void)out_size; (void)ws_size;
  const float* feat = (const float*)d_in[0];
  const float* W0 = (const float*)d_in[1];
  const float* b0 = (const float*)d_in[2];
  const float* W1 = (const float*)d_in[3];
  const float* b1 = (const float*)d_in[4];
  const float* W2 = (const float*)d_in[5];
  const float* b2 = (const float*)d_in[6];
  const int* src = (const int*)d_in[7];
  const int* dst = (const int*)d_in[8];
  float* out = (float*)d_out;

  // workspace layout (~33 MB)
  char* p = (char*)d_ws;
  int* out_deg = (int*)p;   p += (size_t)NN * 4;
  int* in_deg  = (int*)p;   p += (size_t)NN * 4;
  float* out_norm = (float*)p; p += (size_t)NN * 4;
  float* in_norm  = (float*)p; p += (size_t)NN * 4;
  int* row_ptr = (int*)p;   p += (size_t)(NN + 64) * 4;
  int* cursor  = (int*)p;   p += (size_t)NN * 4;
  int* partial = (int*)p;   p += (size_t)256 * 4;
  int* col     = (int*)p;   p += (size_t)NE * 4;
  float* gbuf  = (float*)p; p += (size_t)NN * DD * 4;

  hipMemsetAsync(out_deg, 0, (size_t)NN * 2 * sizeof(int), stream);  // out_deg + in_deg
  hipMemsetAsync(cursor, 0, (size_t)NN * sizeof(int), stream);

  k_degrees<<<(NE + 255) / 256, 256, 0, stream>>>(src, dst, out_deg, in_deg);
  k_norms<<<(NN + 255) / 256, 256, 0, stream>>>(out_deg, in_deg, out_norm, in_norm);
  k_scan_partial<<<NCHUNK, SCAN_B, 0, stream>>>(in_deg, partial);
  k_scan_chunks<<<1, 128, 0, stream>>>(partial, row_ptr);
  k_scan_final<<<NCHUNK, SCAN_B, 0, stream>>>(in_deg, partial, row_ptr);
  k_bucket<<<(NE + 255) / 256, 256, 0, stream>>>(src, dst, row_ptr, cursor, col);

  const float* xs[3] = {feat, out, out};
  const float* Wl[3] = {W0, W1, W2};
  const float* bl[3] = {b0, b1, b2};
  for (int l = 0; l < 3; ++l) {
    k_gemm<<<1024, 256, 0, stream>>>(xs[l], out_norm, Wl[l], gbuf);
    k_agg<<<2048, 256, 0, stream>>>(gbuf, row_ptr, col, in_norm, bl[l], out);
  }
}

// Round 3
// 484.904 us; speedup vs baseline: 1.5263x; 1.1406x over previous
//
#include <hip/hip_runtime.h>
#include <math.h>

#define NN 100000
#define NE 1200000
#define DD 64
#define STRIDE 64   // ELL row stride; P(Poisson(12) >= 64) ~ 1e-28 -> safe

// ---- fused degree-count + ELL bucket build ----
// cursor[] doubles as in_deg afterwards; eliminates the scan + second
// src/dst pass entirely. 2.4M device atomics (down from 3.6M).
__global__ __launch_bounds__(256) void k_build(const int* __restrict__ src,
                                               const int* __restrict__ dst,
                                               int* __restrict__ out_deg,
                                               int* __restrict__ cursor,
                                               int* __restrict__ ell) {
  int e = blockIdx.x * blockDim.x + threadIdx.x;
  if (e < NE) {
    int s = src[e];
    int d = dst[e];
    atomicAdd(&out_deg[s], 1);
    int p = atomicAdd(&cursor[d], 1);
    if (p < STRIDE) ell[(size_t)d * STRIDE + p] = s;   // guard: never corrupt
  }
}

// ---- norms ----
__global__ __launch_bounds__(256) void k_norms(const int* __restrict__ out_deg,
                                               const int* __restrict__ in_deg,
                                               float* __restrict__ out_norm,
                                               float* __restrict__ in_norm) {
  int i = blockIdx.x * blockDim.x + threadIdx.x;
  if (i < NN) {
    out_norm[i] = rsqrtf(fmaxf((float)out_deg[i], 1.0f));
    in_norm[i]  = rsqrtf(fmaxf((float)in_deg[i], 1.0f));
  }
}

// ---- g = (x * out_norm[:,None]) @ W : wave per row, W column in regs ----
__global__ __launch_bounds__(256) void k_gemm(const float* __restrict__ x,
                                              const float* __restrict__ onorm,
                                              const float* __restrict__ W,
                                              float* __restrict__ g) {
  const int lane = threadIdx.x & 63;
  const int wave = (blockIdx.x * blockDim.x + threadIdx.x) >> 6;
  const int nw = (gridDim.x * blockDim.x) >> 6;
  float w[DD];
#pragma unroll
  for (int k = 0; k < DD; ++k) w[k] = W[k * DD + lane];
  for (int r = wave; r < NN; r += nw) {
    float xr = x[r * DD + lane] * onorm[r];
    float acc = 0.0f;
#pragma unroll
    for (int k = 0; k < DD; ++k) acc = fmaf(__shfl(xr, k), w[k], acc);
    g[r * DD + lane] = acc;
  }
}

// ---- out[v] = elu(in_norm[v] * sum_{e in ELL[v]} g[ell[e]] + b) ----
// 8 edges/iter: 2 aligned int4 col loads + 8 independent 256-B row loads in
// flight (MLP for the latency-bound gather). Indices clamped to 0 BEFORE
// address formation so uninitialized ELL slots are never dereferenced.
__global__ __launch_bounds__(256) void k_agg(const float* __restrict__ g,
                                             const int* __restrict__ ell,
                                             const int* __restrict__ indeg,
                                             const float* __restrict__ in_norm,
                                             const float* __restrict__ bias,
                                             float* __restrict__ out) {
  const int lane = threadIdx.x & 63;
  const int wave = (blockIdx.x * blockDim.x + threadIdx.x) >> 6;
  const int nw = (gridDim.x * blockDim.x) >> 6;
  const float b = bias[lane];
  for (int v = wave; v < NN; v += nw) {
    const int deg = min(indeg[v], STRIDE);
    const int* row = ell + (size_t)v * STRIDE;
    float acc = 0.0f;
    for (int j = 0; j < deg; j += 8) {
      const int4 c0 = *(const int4*)(row + j);
      const int4 c1 = *(const int4*)(row + j + 4);
      const int s0 = c0.x;                            // j < deg always
      const int s1 = (j + 1 < deg) ? c0.y : 0;
      const int s2 = (j + 2 < deg) ? c0.z : 0;
      const int s3 = (j + 3 < deg) ? c0.w : 0;
      const int s4 = (j + 4 < deg) ? c1.x : 0;
      const int s5 = (j + 5 < deg) ? c1.y : 0;
      const int s6 = (j + 6 < deg) ? c1.z : 0;
      const int s7 = (j + 7 < deg) ? c1.w : 0;
      const float v0 = g[(size_t)s0 * DD + lane];
      const float v1 = g[(size_t)s1 * DD + lane];
      const float v2 = g[(size_t)s2 * DD + lane];
      const float v3 = g[(size_t)s3 * DD + lane];
      const float v4 = g[(size_t)s4 * DD + lane];
      const float v5 = g[(size_t)s5 * DD + lane];
      const float v6 = g[(size_t)s6 * DD + lane];
      const float v7 = g[(size_t)s7 * DD + lane];
      acc += v0;
      acc += (j + 1 < deg) ? v1 : 0.0f;
      acc += (j + 2 < deg) ? v2 : 0.0f;
      acc += (j + 3 < deg) ? v3 : 0.0f;
      acc += (j + 4 < deg) ? v4 : 0.0f;
      acc += (j + 5 < deg) ? v5 : 0.0f;
      acc += (j + 6 < deg) ? v6 : 0.0f;
      acc += (j + 7 < deg) ? v7 : 0.0f;
    }
    float r = fmaf(acc, in_norm[v], b);
    out[v * DD + lane] = (r > 0.0f) ? r : expm1f(r);
  }
}

extern "C" void kernel_launch(void* const* d_in, const int* in_sizes, int n_in,
                              void* d_out, int out_size, void* d_ws, size_t ws_size,
                              hipStream_t stream) {
  (void)in_sizes; (void)n_in; (void)out_size; (void)ws_size;
  const float* feat = (const float*)d_in[0];
  const float* W0 = (const float*)d_in[1];
  const float* b0 = (const float*)d_in[2];
  const float* W1 = (const float*)d_in[3];
  const float* b1 = (const float*)d_in[4];
  const float* W2 = (const float*)d_in[5];
  const float* b2 = (const float*)d_in[6];
  const int* src = (const int*)d_in[7];
  const int* dst = (const int*)d_in[8];
  float* out = (float*)d_out;

  // workspace layout (~53 MB)
  char* p = (char*)d_ws;
  int* out_deg = (int*)p;      p += (size_t)NN * 4;   // }
  int* cursor  = (int*)p;      p += (size_t)NN * 4;   // } one contiguous memset
  float* out_norm = (float*)p; p += (size_t)NN * 4;
  float* in_norm  = (float*)p; p += (size_t)NN * 4;
  int* ell     = (int*)p;      p += (size_t)NN * STRIDE * 4;   // 25.6 MB
  float* gbuf  = (float*)p;    p += (size_t)NN * DD * 4;       // 25.6 MB

  hipMemsetAsync(out_deg, 0, (size_t)NN * 2 * sizeof(int), stream);  // out_deg+cursor

  k_build<<<(NE + 255) / 256, 256, 0, stream>>>(src, dst, out_deg, cursor, ell);
  k_norms<<<(NN + 255) / 256, 256, 0, stream>>>(out_deg, cursor, out_norm, in_norm);

  const float* xs[3] = {feat, out, out};
  const float* Wl[3] = {W0, W1, W2};
  const float* bl[3] = {b0, b1, b2};
  for (int l = 0; l < 3; ++l) {
    k_gemm<<<1024, 256, 0, stream>>>(xs[l], out_norm, Wl[l], gbuf);
    k_agg<<<2048, 256, 0, stream>>>(gbuf, ell, cursor, in_norm, bl[l], out);
  }
}

// Round 5
// 415.819 us; speedup vs baseline: 1.7799x; 1.1661x over previous
//
#include <hip/hip_runtime.h>
#include <math.h>

#define NN 100000
#define NE 1200000
#define DD 64
#define STRIDE 64     // ELL row stride; P(Poisson(12) >= 64) ~ 1e-28, guarded anyway
#define GB 4688       // build blocks in hybrid (1 edge/thread, 4688*256 >= NE)
#define GG 1024       // gemm blocks in hybrid

__device__ __forceinline__ float bcast_lane(float v, int k) {
  return __uint_as_float(__builtin_amdgcn_readlane(__float_as_uint(v), (unsigned)k));
}

// ---- hybrid: {degree-count + ELL build} || {y0 = feat @ W0, unnormalized} ----
// Build blocks are atomic-latency-bound (VALU ~0.4% busy); gemm blocks are pure
// VALU. Co-scheduling them in one dispatch hides gemm0 under the build.
__global__ __launch_bounds__(256) void k_hybrid(const int* __restrict__ src,
                                                const int* __restrict__ dst,
                                                int* __restrict__ out_deg,
                                                int* __restrict__ cursor,
                                                int* __restrict__ ell,
                                                const float* __restrict__ feat,
                                                const float* __restrict__ W0,
                                                float* __restrict__ y0) {
  __shared__ float Wl[DD * DD];
  if (blockIdx.x < GB) {
    int e = blockIdx.x * 256 + threadIdx.x;
    if (e < NE) {
      int s = src[e];
      int d = dst[e];
      atomicAdd(&out_deg[s], 1);
      int p = atomicAdd(&cursor[d], 1);
      if (p < STRIDE) ell[(size_t)d * STRIDE + p] = s;   // never corrupt
    }
  } else {
    for (int i = threadIdx.x; i < DD * DD; i += 256) Wl[i] = W0[i];
    __syncthreads();
    const int lane = threadIdx.x & 63;
    const int wv = ((blockIdx.x - GB) * 256 + threadIdx.x) >> 6;
    const int nw = (GG * 256) >> 6;
    for (int r = wv; r < NN; r += nw) {
      float xr = feat[(size_t)r * DD + lane];
      float acc = 0.0f;
#pragma unroll
      for (int k = 0; k < DD; ++k)
        acc = fmaf(bcast_lane(xr, k), Wl[k * DD + lane], acc);
      y0[(size_t)r * DD + lane] = acc;
    }
  }
}

// ---- norms + in-place scale g0 = y0 * out_norm[:,None] (wave per node) ----
__global__ __launch_bounds__(256) void k_norms_scale(const int* __restrict__ out_deg,
                                                     const int* __restrict__ in_deg,
                                                     float* __restrict__ out_norm,
                                                     float* __restrict__ in_norm,
                                                     float* __restrict__ y0) {
  const int lane = threadIdx.x & 63;
  const int wv = (blockIdx.x * 256 + threadIdx.x) >> 6;
  const int nw = (gridDim.x * 256) >> 6;
  for (int v = wv; v < NN; v += nw) {
    float on = rsqrtf(fmaxf((float)out_deg[v], 1.0f));
    float inn = rsqrtf(fmaxf((float)in_deg[v], 1.0f));
    if (lane == 0) { out_norm[v] = on; in_norm[v] = inn; }
    y0[(size_t)v * DD + lane] *= on;
  }
}

// ---- fused: z = inorm*sum_ELL g + b; x = elu(z); (non-last) write (x*onorm)@Wn ----
// Gather: 8 edges/iter, 2 aligned int4 col loads + 8 independent 256-B row
// loads in flight; clamped indices before address formation (ELL slots past
// deg are uninitialized). Epilogue gemm: W_next staged in LDS, readlane
// broadcast -> 64 FMAs, hidden under gather latency.
template <bool LAST>
__global__ __launch_bounds__(256) void k_agg_fused(const float* __restrict__ g,
                                                   const int* __restrict__ ell,
                                                   const int* __restrict__ indeg,
                                                   const float* __restrict__ in_norm,
                                                   const float* __restrict__ out_norm,
                                                   const float* __restrict__ bias,
                                                   const float* __restrict__ Wn,
                                                   float* __restrict__ out) {
  __shared__ float Wl[DD * DD];
  if (!LAST) {
    for (int i = threadIdx.x; i < DD * DD; i += 256) Wl[i] = Wn[i];
    __syncthreads();
  }
  const int lane = threadIdx.x & 63;
  const int wv = (blockIdx.x * 256 + threadIdx.x) >> 6;
  const int nw = (gridDim.x * 256) >> 6;
  const float b = bias[lane];
  for (int v = wv; v < NN; v += nw) {
    const int deg = min(indeg[v], STRIDE);
    const int* row = ell + (size_t)v * STRIDE;
    float acc = 0.0f;
    for (int j = 0; j < deg; j += 8) {
      const int4 c0 = *(const int4*)(row + j);
      const int4 c1 = *(const int4*)(row + j + 4);
      const int s0 = c0.x;                           // j < deg always
      const int s1 = (j + 1 < deg) ? c0.y : 0;
      const int s2 = (j + 2 < deg) ? c0.z : 0;
      const int s3 = (j + 3 < deg) ? c0.w : 0;
      const int s4 = (j + 4 < deg) ? c1.x : 0;
      const int s5 = (j + 5 < deg) ? c1.y : 0;
      const int s6 = (j + 6 < deg) ? c1.z : 0;
      const int s7 = (j + 7 < deg) ? c1.w : 0;
      const float v0 = g[(size_t)s0 * DD + lane];
      const float v1 = g[(size_t)s1 * DD + lane];
      const float v2 = g[(size_t)s2 * DD + lane];
      const float v3 = g[(size_t)s3 * DD + lane];
      const float v4 = g[(size_t)s4 * DD + lane];
      const float v5 = g[(size_t)s5 * DD + lane];
      const float v6 = g[(size_t)s6 * DD + lane];
      const float v7 = g[(size_t)s7 * DD + lane];
      acc += v0;
      acc += (j + 1 < deg) ? v1 : 0.0f;
      acc += (j + 2 < deg) ? v2 : 0.0f;
      acc += (j + 3 < deg) ? v3 : 0.0f;
      acc += (j + 4 < deg) ? v4 : 0.0f;
      acc += (j + 5 < deg) ? v5 : 0.0f;
      acc += (j + 6 < deg) ? v6 : 0.0f;
      acc += (j + 7 < deg) ? v7 : 0.0f;
    }
    float z = fmaf(acc, in_norm[v], b);
    float x = (z > 0.0f) ? z : expm1f(z);
    if (LAST) {
      out[(size_t)v * DD + lane] = x;
    } else {
      float xs = x * out_norm[v];
      float a2 = 0.0f;
#pragma unroll
      for (int k = 0; k < DD; ++k)
        a2 = fmaf(bcast_lane(xs, k), Wl[k * DD + lane], a2);
      out[(size_t)v * DD + lane] = a2;
    }
  }
}

extern "C" void kernel_launch(void* const* d_in, const int* in_sizes, int n_in,
                              void* d_out, int out_size, void* d_ws, size_t ws_size,
                              hipStream_t stream) {
  (void)in_sizes; (void)n_in; (void)out_size; (void)ws_size;
  const float* feat = (const float*)d_in[0];
  const float* W0 = (const float*)d_in[1];
  const float* b0 = (const float*)d_in[2];
  const float* W1 = (const float*)d_in[3];
  const float* b1 = (const float*)d_in[4];
  const float* W2 = (const float*)d_in[5];
  const float* b2 = (const float*)d_in[6];
  const int* src = (const int*)d_in[7];
  const int* dst = (const int*)d_in[8];
  float* out = (float*)d_out;

  // workspace layout (~53 MB)
  char* p = (char*)d_ws;
  int* out_deg = (int*)p;      p += (size_t)NN * 4;   // }
  int* cursor  = (int*)p;      p += (size_t)NN * 4;   // } one contiguous memset
  float* out_norm = (float*)p; p += (size_t)NN * 4;
  float* in_norm  = (float*)p; p += (size_t)NN * 4;
  int* ell     = (int*)p;      p += (size_t)NN * STRIDE * 4;   // 25.6 MB
  float* gbuf  = (float*)p;    p += (size_t)NN * DD * 4;       // 25.6 MB

  hipMemsetAsync(out_deg, 0, (size_t)NN * 2 * sizeof(int), stream);  // out_deg+cursor

  // build || gemm0 (y0 = feat @ W0, unnormalized) in one dispatch
  k_hybrid<<<GB + GG, 256, 0, stream>>>(src, dst, out_deg, cursor, ell,
                                        feat, W0, gbuf);
  // norms + g0 = y0 * out_norm
  k_norms_scale<<<512, 256, 0, stream>>>(out_deg, cursor, out_norm, in_norm, gbuf);

  // layer 0: gather g0 -> elu -> (*onorm) @ W1  => g1 in d_out
  k_agg_fused<false><<<2048, 256, 0, stream>>>(gbuf, ell, cursor, in_norm,
                                               out_norm, b0, W1, out);
  // layer 1: gather g1 -> elu -> (*onorm) @ W2  => g2 in gbuf
  k_agg_fused<false><<<2048, 256, 0, stream>>>(out, ell, cursor, in_norm,
                                               out_norm, b1, W2, gbuf);
  // layer 2: gather g2 -> elu => final output
  k_agg_fused<true><<<2048, 256, 0, stream>>>(gbuf, ell, cursor, in_norm,
                                              out_norm, b2, nullptr, out);
}